// Round 1
// 161.401 us; speedup vs baseline: 1.0241x; 1.0241x over previous
//
#include <hip/hip_runtime.h>

// GCN 2-layer. R13: replace 3-phase no-atomic counting sort (p1 hist -> p2
// prefix -> p3 scatter; 20MB of ghist/boff bookkeeping traffic + latency-
// exposed 79-block prefix walk) with a single global-atomic scatter build.
// Edge order within a node bucket is irrelevant (commutative fp32 sum), so
// rank = atomicAdd(&cnt[d],1) is sufficient. u16 bucket table (R12) keeps the
// scatter's dirty footprint L2-resident per XCD. Also fuses the two agg128
// half-passes into one launch (sequential halves: half-0 blocks dispatch
// first so each XCD L2 holds only one 2.56MB G at a time).
// Pipeline: memset(cnt) -> k_build(scatter || WT transpose) -> k_g1(gemm1)
//           -> k_agg128f -> k_mgemm2 -> k_agg64.   6 enqueues vs 7.

#define N_NODES 20000
#define N_EDGES 640000
#define IN_DIM 128
#define HID_DIM 128
#define OUT_DIM 64

#define STRIDE 80
#define SCAT_NB (N_EDGES / 256)                   // 2500 scatter blocks
#define WT_NB ((128 * 128 + 64 * 128) / 256)      // 96 (exact)
#define GEMM1_NB ((2 * (N_NODES / 16) + 3) / 4)   // 625
#define AGG_NB ((N_NODES + 3) / 4)                // 5000

typedef _Float16 half8_t __attribute__((ext_vector_type(8)));
typedef float float4_t __attribute__((ext_vector_type(4)));

// k_build: blocks [0,SCAT_NB) do the atomic scatter (1 edge/thread: rank via
// global atomicAdd on cnt, u16 store into padded bucket); blocks
// [SCAT_NB, SCAT_NB+WT_NB) transpose+cast W1/W2 -> fp16 WT[col][k].
__global__ __launch_bounds__(256) void k_build(const int* __restrict__ src,
                                               const int* __restrict__ dst,
                                               int* __restrict__ cnt,
                                               unsigned short* __restrict__ esrc_pad,
                                               const float* __restrict__ W1,
                                               const float* __restrict__ W2,
                                               _Float16* __restrict__ WT1,
                                               _Float16* __restrict__ WT2) {
    const int b = blockIdx.x, tid = threadIdx.x;
    if (b < SCAT_NB) {
        const int e = b * 256 + tid;
        const int s = src[e], d = dst[e];
        unsigned int rank = atomicAdd((unsigned int*)&cnt[d], 1u);
        if (rank < STRIDE) esrc_pad[d * STRIDE + rank] = (unsigned short)s;
    } else {
        int i = (b - SCAT_NB) * 256 + tid;
        if (i < 128 * 128) {
            int c = i >> 7, k = i & 127;
            WT1[i] = (_Float16)W1[k * 128 + c];
        } else {
            int o = i - 128 * 128;
            int c = o >> 7, k = o & 127;
            WT2[o] = (_Float16)W2[k * 64 + c];
        }
    }
}

// gemm1: g = rsqrt(cnt+1)*(x@W1), MFMA f16, column-blocked GA/GB halves.
__global__ __launch_bounds__(256) void k_g1(const float* __restrict__ A,
                                            const _Float16* __restrict__ WT,
                                            const int* __restrict__ cnt,
                                            _Float16* __restrict__ GA,
                                            _Float16* __restrict__ GB) {
    const int wave = threadIdx.x >> 6;
    const int lane = threadIdx.x & 63;
    const int task = blockIdx.x * 4 + wave;
    if (task >= 2 * (N_NODES / 16)) return;
    const int strip = task >> 1;
    const int nh = task & 1;
    const int row0 = strip * 16;
    const int mrow = row0 + (lane & 15);
    const int kq = (lane >> 4) * 8;
    _Float16* G = nh ? GB : GA;

    half8_t af[4];
#pragma unroll
    for (int kc = 0; kc < 4; ++kc) {
        const float* ap = A + (size_t)mrow * 128 + kc * 32 + kq;
        float4_t f0 = *(const float4_t*)ap;
        float4_t f1 = *(const float4_t*)(ap + 4);
        half8_t h;
        h[0] = (_Float16)f0[0]; h[1] = (_Float16)f0[1];
        h[2] = (_Float16)f0[2]; h[3] = (_Float16)f0[3];
        h[4] = (_Float16)f1[0]; h[5] = (_Float16)f1[1];
        h[6] = (_Float16)f1[2]; h[7] = (_Float16)f1[3];
        af[kc] = h;
    }

    float4_t acc[4];
#pragma unroll
    for (int nt = 0; nt < 4; ++nt) acc[nt] = (float4_t)(0.0f);
#pragma unroll
    for (int nt = 0; nt < 4; ++nt) {
        const _Float16* wp = WT + (size_t)((nh * 4 + nt) * 16 + (lane & 15)) * 128 + kq;
#pragma unroll
        for (int kc = 0; kc < 4; ++kc) {
            half8_t bf = *(const half8_t*)(wp + kc * 32);
            acc[nt] = __builtin_amdgcn_mfma_f32_16x16x32_f16(af[kc], bf, acc[nt], 0, 0, 0);
        }
    }
#pragma unroll
    for (int r = 0; r < 4; ++r) {
        int row = row0 + (lane >> 4) * 4 + r;
        float dv = rsqrtf((float)cnt[row] + 1.0f);
#pragma unroll
        for (int nt = 0; nt < 4; ++nt)
            G[(size_t)row * 64 + nt * 16 + (lane & 15)] = (_Float16)(dv * acc[nt][r]);
    }
}

// GEMM2: g2 = rsqrt(cnt+1) * (h1p @ W2), A fp16 direct, out fp16.
__global__ __launch_bounds__(256) void k_mgemm2(const _Float16* __restrict__ A,
                                                const _Float16* __restrict__ WT,
                                                const int* __restrict__ cnt,
                                                _Float16* __restrict__ G) {
    const int wave = threadIdx.x >> 6;
    const int lane = threadIdx.x & 63;
    const int task = blockIdx.x * 4 + wave;
    if (task >= 2 * (N_NODES / 16)) return;
    const int strip = task >> 1;
    const int nh = task & 1;
    const int row0 = strip * 16;
    const int mrow = row0 + (lane & 15);
    const int kq = (lane >> 4) * 8;

    half8_t af[4];
#pragma unroll
    for (int kc = 0; kc < 4; ++kc)
        af[kc] = *(const half8_t*)(A + (size_t)mrow * 128 + kc * 32 + kq);

    float4_t acc[2];
#pragma unroll
    for (int nt = 0; nt < 2; ++nt) acc[nt] = (float4_t)(0.0f);
#pragma unroll
    for (int nt = 0; nt < 2; ++nt) {
        const _Float16* wp = WT + (size_t)((nh * 2 + nt) * 16 + (lane & 15)) * 128 + kq;
#pragma unroll
        for (int kc = 0; kc < 4; ++kc) {
            half8_t bf = *(const half8_t*)(wp + kc * 32);
            acc[nt] = __builtin_amdgcn_mfma_f32_16x16x32_f16(af[kc], bf, acc[nt], 0, 0, 0);
        }
    }
#pragma unroll
    for (int r = 0; r < 4; ++r) {
        int row = row0 + (lane >> 4) * 4 + r;
        float dv = rsqrtf((float)cnt[row] + 1.0f);
#pragma unroll
        for (int nt = 0; nt < 2; ++nt)
            G[(size_t)row * 64 + (nh * 2 + nt) * 16 + (lane & 15)] =
                (_Float16)(dv * acc[nt][r]);
    }
}

// agg128 fused both halves: blocks [0,AGG_NB) do cols [0,64) from Ga,
// blocks [AGG_NB,2*AGG_NB) do cols [64,128) from Gb. Sequential halves keep
// each XCD's L2 working set to one 2.56MB G table at a time.
// One wave/node, 8 edges/iter. Writes h1p biased+relu'd.
__global__ __launch_bounds__(256) void k_agg128f(const int* __restrict__ cnt,
                                                 const unsigned short* __restrict__ esrc_pad,
                                                 const _Float16* __restrict__ Ga,
                                                 const _Float16* __restrict__ Gb,
                                                 const float* __restrict__ bias,
                                                 _Float16* __restrict__ out) {
    const int half = (blockIdx.x >= AGG_NB) ? 1 : 0;
    const int bb = blockIdx.x - half * AGG_NB;
    const int wave = threadIdx.x >> 6;
    const int lane = threadIdx.x & 63;
    const int node = bb * 4 + wave;
    if (node >= N_NODES) return;
    const _Float16* __restrict__ G = half ? Gb : Ga;
    const int COL0 = half << 6;
    const int eidx = lane >> 3;
    const int flane = lane & 7;

    const int end = cnt[node];
    const int base = node * STRIDE;

    float acc[8];
#pragma unroll
    for (int p = 0; p < 8; ++p) acc[p] = 0.0f;
    if (lane < 8) {
        half8_t s = *(const half8_t*)(G + (size_t)node * 64 + flane * 8);
#pragma unroll
        for (int p = 0; p < 8; ++p) acc[p] = (float)s[p];
    }

    int j = 0;
    for (; j + 7 < end; j += 8) {
        int s = (int)esrc_pad[base + j + eidx];
        half8_t r = *(const half8_t*)(G + (size_t)s * 64 + flane * 8);
#pragma unroll
        for (int p = 0; p < 8; ++p) acc[p] += (float)r[p];
    }
    if (j < end) {
        int idx = j + eidx;
        int s = (int)esrc_pad[base + ((idx < end) ? idx : (end - 1))];
        float valid = (idx < end) ? 1.0f : 0.0f;
        half8_t r = *(const half8_t*)(G + (size_t)s * 64 + flane * 8);
#pragma unroll
        for (int p = 0; p < 8; ++p) acc[p] += valid * (float)r[p];
    }

#pragma unroll
    for (int p = 0; p < 8; ++p) {
        acc[p] += __shfl_xor(acc[p], 32, 64);
        acc[p] += __shfl_xor(acc[p], 16, 64);
        acc[p] += __shfl_xor(acc[p], 8, 64);
    }

    if (lane < 8) {
        float dv = rsqrtf((float)end + 1.0f);
        float4_t b0 = *(const float4_t*)(bias + COL0 + flane * 8);
        float4_t b1 = *(const float4_t*)(bias + COL0 + flane * 8 + 4);
        half8_t o;
        o[0] = (_Float16)fmaxf(acc[0] * dv + b0[0], 0.0f);
        o[1] = (_Float16)fmaxf(acc[1] * dv + b0[1], 0.0f);
        o[2] = (_Float16)fmaxf(acc[2] * dv + b0[2], 0.0f);
        o[3] = (_Float16)fmaxf(acc[3] * dv + b0[3], 0.0f);
        o[4] = (_Float16)fmaxf(acc[4] * dv + b1[0], 0.0f);
        o[5] = (_Float16)fmaxf(acc[5] * dv + b1[1], 0.0f);
        o[6] = (_Float16)fmaxf(acc[6] * dv + b1[2], 0.0f);
        o[7] = (_Float16)fmaxf(acc[7] * dv + b1[3], 0.0f);
        *(half8_t*)(out + (size_t)node * 128 + COL0 + flane * 8) = o;
    }
}

// F=64 agg: one wave/node, 8 edges/iter. Epilogue: *dinv, +bias, fp32 out.
__global__ __launch_bounds__(256) void k_agg64(const int* __restrict__ cnt,
                                               const unsigned short* __restrict__ esrc_pad,
                                               const _Float16* __restrict__ g,
                                               const float* __restrict__ bias,
                                               float* __restrict__ out) {
    const int wave = threadIdx.x >> 6;
    const int lane = threadIdx.x & 63;
    const int node = blockIdx.x * 4 + wave;
    if (node >= N_NODES) return;
    const int eidx = lane >> 3;
    const int flane = lane & 7;

    const int end = cnt[node];
    const int base = node * STRIDE;

    float acc[8];
#pragma unroll
    for (int p = 0; p < 8; ++p) acc[p] = 0.0f;
    if (lane < 8) {
        half8_t s = *(const half8_t*)(g + (size_t)node * 64 + flane * 8);
#pragma unroll
        for (int p = 0; p < 8; ++p) acc[p] = (float)s[p];
    }

    int j = 0;
    for (; j + 7 < end; j += 8) {
        int s = (int)esrc_pad[base + j + eidx];
        half8_t r = *(const half8_t*)(g + (size_t)s * 64 + flane * 8);
#pragma unroll
        for (int p = 0; p < 8; ++p) acc[p] += (float)r[p];
    }
    if (j < end) {
        int idx = j + eidx;
        int s = (int)esrc_pad[base + ((idx < end) ? idx : (end - 1))];
        float valid = (idx < end) ? 1.0f : 0.0f;
        half8_t r = *(const half8_t*)(g + (size_t)s * 64 + flane * 8);
#pragma unroll
        for (int p = 0; p < 8; ++p) acc[p] += valid * (float)r[p];
    }

#pragma unroll
    for (int p = 0; p < 8; ++p) {
        acc[p] += __shfl_xor(acc[p], 32, 64);
        acc[p] += __shfl_xor(acc[p], 16, 64);
        acc[p] += __shfl_xor(acc[p], 8, 64);
    }

    if (lane < 8) {
        float dv = rsqrtf((float)end + 1.0f);
        float4_t b0 = *(const float4_t*)(bias + flane * 8);
        float4_t b1 = *(const float4_t*)(bias + flane * 8 + 4);
        float4_t o0, o1;
        o0[0] = acc[0] * dv + b0[0]; o0[1] = acc[1] * dv + b0[1];
        o0[2] = acc[2] * dv + b0[2]; o0[3] = acc[3] * dv + b0[3];
        o1[0] = acc[4] * dv + b1[0]; o1[1] = acc[5] * dv + b1[1];
        o1[2] = acc[6] * dv + b1[2]; o1[3] = acc[7] * dv + b1[3];
        *(float4_t*)(out + (size_t)node * 64 + flane * 8) = o0;
        *(float4_t*)(out + (size_t)node * 64 + flane * 8 + 4) = o1;
    }
}

extern "C" void kernel_launch(void* const* d_in, const int* in_sizes, int n_in,
                              void* d_out, int out_size, void* d_ws, size_t ws_size,
                              hipStream_t stream) {
    const float* x  = (const float*)d_in[0];
    const int*   ei = (const int*)d_in[1];
    const float* W1 = (const float*)d_in[2];
    const float* b1 = (const float*)d_in[3];
    const float* W2 = (const float*)d_in[4];
    const float* b2 = (const float*)d_in[5];

    const int* src = ei;
    const int* dst = ei + N_EDGES;

    char* w = (char*)d_ws;
    unsigned short* esrc_pad = (unsigned short*)w; w += sizeof(unsigned short) * (size_t)N_NODES * STRIDE;
    _Float16*       g1a      = (_Float16*)w;       w += sizeof(_Float16) * (size_t)N_NODES * 64;
    _Float16*       g1b      = (_Float16*)w;       w += sizeof(_Float16) * (size_t)N_NODES * 64;
    _Float16*       h1p      = (_Float16*)w;       w += sizeof(_Float16) * (size_t)N_NODES * HID_DIM;
    _Float16*       g2       = (_Float16*)w;       w += sizeof(_Float16) * (size_t)N_NODES * OUT_DIM;
    _Float16*       WT1      = (_Float16*)w;       w += sizeof(_Float16) * 128 * 128;
    _Float16*       WT2      = (_Float16*)w;       w += sizeof(_Float16) * 64 * 128;
    int*            cnt      = (int*)w;            w += sizeof(int) * N_NODES;
    float*          out      = (float*)d_out;

    // Atomic scatter build (rank order within a bucket is irrelevant: the
    // downstream aggregation is a commutative fp32 sum).
    hipMemsetAsync(cnt, 0, sizeof(int) * N_NODES, stream);
    k_build<<<SCAT_NB + WT_NB, 256, 0, stream>>>(src, dst, cnt, esrc_pad, W1, W2, WT1, WT2);

    // Layer 1 GEMM (needs WT1 + cnt) then fused-halves aggregation
    k_g1<<<GEMM1_NB, 256, 0, stream>>>(x, WT1, cnt, g1a, g1b);
    k_agg128f<<<2 * AGG_NB, 256, 0, stream>>>(cnt, esrc_pad, g1a, g1b, b1, h1p);

    // Layer 2
    k_mgemm2<<<GEMM1_NB, 256, 0, stream>>>(h1p, WT2, cnt, g2);
    k_agg64<<<AGG_NB, 256, 0, stream>>>(cnt, esrc_pad, g2, b2, out);
}